// Round 1
// baseline (762.916 us; speedup 1.0000x reference)
//
#include <hip/hip_runtime.h>

// Child-Sum Tree-LSTM fused kernel, MI355X/gfx950.
// Strategy: split-fp32-into-bf16(hi,lo), 3x MFMA (hh, lh, hl) for ~fp32 accuracy.
// One fused kernel: no intermediates to HBM. 704 MB total traffic (memory-bound target).

#define NN 131072          // nodes
#define LDSS 136           // LDS row stride in bf16 elems (128 + 8 pad -> conflict-free frag reads)

typedef __attribute__((ext_vector_type(8))) short bf16x8;
typedef __attribute__((ext_vector_type(4))) float f32x4;

// d_ws layout, in ushort (bf16) units. Weights pre-split + pre-swizzled to MFMA-B fragment order.
#define BX_HI 0            // [W_iou | W_f] : 128 x 512
#define BX_LO 65536
#define BH_HI 131072       // U_iou : 128 x 384
#define BH_LO 180224
#define UF_HI 229376       // U_f : 128 x 128
#define UF_LO 245760
// total 262144 ushort = 512 KB of d_ws

__device__ __forceinline__ unsigned short f2bf(float f){
  unsigned int u = __float_as_uint(f);
  u += 0x7FFFu + ((u >> 16) & 1u);   // round-to-nearest-even
  return (unsigned short)(u >> 16);
}
__device__ __forceinline__ float bf2f(unsigned short h){
  return __uint_as_float(((unsigned int)h) << 16);
}
__device__ __forceinline__ float sigm(float v){ return 1.f / (1.f + __expf(-v)); }
__device__ __forceinline__ float tanh_f(float v){
  float a = fabsf(v);
  float e = __expf(-2.f * a);
  float r = (1.f - e) / (1.f + e);
  return copysignf(r, v);
}

// Split 8 floats into hi/lo bf16 and store 16B each to LDS (conflict-free layout).
__device__ __forceinline__ void split8_store(unsigned short* hp, unsigned short* lp,
                                             const float* v){
  unsigned short h[8], l[8];
#pragma unroll
  for (int i = 0; i < 8; ++i){
    h[i] = f2bf(v[i]);
    l[i] = f2bf(v[i] - bf2f(h[i]));
  }
  uint4 uh, ul;
  uh.x = (unsigned)h[0] | ((unsigned)h[1] << 16);
  uh.y = (unsigned)h[2] | ((unsigned)h[3] << 16);
  uh.z = (unsigned)h[4] | ((unsigned)h[5] << 16);
  uh.w = (unsigned)h[6] | ((unsigned)h[7] << 16);
  ul.x = (unsigned)l[0] | ((unsigned)l[1] << 16);
  ul.y = (unsigned)l[2] | ((unsigned)l[3] << 16);
  ul.z = (unsigned)l[4] | ((unsigned)l[5] << 16);
  ul.w = (unsigned)l[6] | ((unsigned)l[7] << 16);
  *(uint4*)hp = uh;
  *(uint4*)lp = ul;
}

// ---- prep: split weights to hi/lo bf16, swizzled into MFMA-B fragment order ----
// frag addr for (k,col): kc=k>>5, q=(k>>3)&3, j=k&7, nc=col>>4, cc=col&15, lane=q*16+cc
// addr = ((kc*NT + nc)*64 + lane)*8 + j      -> per-(kc,nc) tile a wave loads 16B/lane coalesced.
__global__ void prep_weights(const float* __restrict__ Wiou, const float* __restrict__ Uiou,
                             const float* __restrict__ Wf, const float* __restrict__ Uf,
                             unsigned short* __restrict__ ws){
  int tid = blockIdx.x * 256 + threadIdx.x;  // 0 .. 131071
  float v; int k, col, nt; unsigned int bhi, blo;
  if (tid < 65536){                       // Bx: 128 x 512 = [W_iou | W_f]
    k = tid >> 9; col = tid & 511;
    v = (col < 384) ? Wiou[k * 384 + col] : Wf[k * 128 + (col - 384)];
    nt = 32; bhi = BX_HI; blo = BX_LO;
  } else if (tid < 65536 + 49152){        // Bh: 128 x 384 = U_iou
    int s = tid - 65536; k = s / 384; col = s - k * 384;
    v = Uiou[k * 384 + col];
    nt = 24; bhi = BH_HI; blo = BH_LO;
  } else {                                // Uf: 128 x 128
    int s = tid - 65536 - 49152; k = s >> 7; col = s & 127;
    v = Uf[k * 128 + col];
    nt = 8; bhi = UF_HI; blo = UF_LO;
  }
  int kc = k >> 5, q = (k >> 3) & 3, j = k & 7;
  int nc = col >> 4, cc = col & 15;
  int lane = q * 16 + cc;
  unsigned int addr = ((unsigned)(kc * nt + nc) * 64u + (unsigned)lane) * 8u + (unsigned)j;
  unsigned short hi = f2bf(v);
  unsigned short lo = f2bf(v - bf2f(hi));
  ws[bhi + addr] = hi;
  ws[blo + addr] = lo;
}

// ---- main fused kernel ----
// block = 256 threads (4 waves), M = 32 nodes/block.
// Wave w owns features [32w, 32w+32) for every gate -> all state stays in-wave.
__launch_bounds__(256, 2)
__global__ void tree_lstm_fused(const float* __restrict__ xg,
                                const float* __restrict__ hcg,
                                const float* __restrict__ ccg,
                                const float* __restrict__ b_iou,
                                const float* __restrict__ b_f,
                                const unsigned short* __restrict__ ws,
                                float* __restrict__ out){
  __shared__ alignas(16) unsigned short AxHi[32 * LDSS];
  __shared__ alignas(16) unsigned short AxLo[32 * LDSS];
  __shared__ alignas(16) unsigned short HkHi[32 * LDSS];
  __shared__ alignas(16) unsigned short HkLo[32 * LDSS];

  const int t = threadIdx.x;
  const int lane = t & 63;
  const int w = t >> 6;          // wave 0..3
  const int m = lane & 15;       // A-frag row / C col (feature)
  const int q = lane >> 4;       // quad
  const int node0 = blockIdx.x * 32;
  const int nc0 = 2 * w;

  // ---- stage x tile as hi/lo bf16 ----
#pragma unroll
  for (int g = 0; g < 2; ++g){
    int idx8 = t + 256 * g;
    int row = idx8 >> 4, col8 = idx8 & 15;
    const float4* s = (const float4*)(xg + (size_t)(node0 + row) * 128 + col8 * 8);
    float4 a = s[0], b = s[1];
    float v[8] = {a.x, a.y, a.z, a.w, b.x, b.y, b.z, b.w};
    split8_store(AxHi + row * LDSS + col8 * 8, AxLo + row * LDSS + col8 * 8, v);
  }
  __syncthreads();

  // ---- GEMM1: x @ [W_iou | W_f]  -> acc[c][rt], c = gate*2+sub, gates {i,o,u,xWf} ----
  const f32x4 zero = {0.f, 0.f, 0.f, 0.f};
  f32x4 acc[8][2];
#pragma unroll
  for (int c = 0; c < 8; ++c)
#pragma unroll
    for (int rt = 0; rt < 2; ++rt) acc[c][rt] = zero;

#pragma unroll
  for (int kc = 0; kc < 4; ++kc){
    bf16x8 ah[2], al[2];
#pragma unroll
    for (int rt = 0; rt < 2; ++rt){
      int off = (rt * 16 + m) * LDSS + kc * 32 + q * 8;
      ah[rt] = *(const bf16x8*)(AxHi + off);
      al[rt] = *(const bf16x8*)(AxLo + off);
    }
#pragma unroll
    for (int c = 0; c < 8; ++c){
      int nc = (c >> 1) * 8 + nc0 + (c & 1);
      bf16x8 bh = *(const bf16x8*)(ws + BX_HI + ((kc * 32 + nc) * 64 + lane) * 8);
      bf16x8 bl = *(const bf16x8*)(ws + BX_LO + ((kc * 32 + nc) * 64 + lane) * 8);
#pragma unroll
      for (int rt = 0; rt < 2; ++rt){
        acc[c][rt] = __builtin_amdgcn_mfma_f32_16x16x32_bf16(ah[rt], bh, acc[c][rt], 0, 0, 0);
        acc[c][rt] = __builtin_amdgcn_mfma_f32_16x16x32_bf16(al[rt], bh, acc[c][rt], 0, 0, 0);
        acc[c][rt] = __builtin_amdgcn_mfma_f32_16x16x32_bf16(ah[rt], bl, acc[c][rt], 0, 0, 0);
      }
    }
  }

  // ---- children: GEMM2 (h_k @ U_f) + fused forget-gate epilogue; accumulate h_sum ----
  float hs[16];
#pragma unroll
  for (int i = 0; i < 16; ++i) hs[i] = 0.f;
  f32x4 fc[2][2];
#pragma unroll
  for (int ct = 0; ct < 2; ++ct)
#pragma unroll
    for (int rt = 0; rt < 2; ++rt) fc[ct][rt] = zero;

  float bfv[2];
#pragma unroll
  for (int ct = 0; ct < 2; ++ct) bfv[ct] = b_f[w * 32 + ct * 16 + m];

  for (int k = 0; k < 4; ++k){
    float v0[8], v1[8];
    {
      int row = t >> 4, col8 = t & 15;
      const float4* s = (const float4*)(hcg + ((size_t)(node0 + row) * 4 + k) * 128 + col8 * 8);
      float4 a = s[0], b = s[1];
      v0[0]=a.x; v0[1]=a.y; v0[2]=a.z; v0[3]=a.w; v0[4]=b.x; v0[5]=b.y; v0[6]=b.z; v0[7]=b.w;
    }
    {
      int idx8 = t + 256; int row = idx8 >> 4, col8 = idx8 & 15;
      const float4* s = (const float4*)(hcg + ((size_t)(node0 + row) * 4 + k) * 128 + col8 * 8);
      float4 a = s[0], b = s[1];
      v1[0]=a.x; v1[1]=a.y; v1[2]=a.z; v1[3]=a.w; v1[4]=b.x; v1[5]=b.y; v1[6]=b.z; v1[7]=b.w;
    }
    __syncthreads();   // previous GEMM2 readers done with Hk
    {
      int row = t >> 4, col8 = t & 15;
      split8_store(HkHi + row * LDSS + col8 * 8, HkLo + row * LDSS + col8 * 8, v0);
    }
    {
      int idx8 = t + 256; int row = idx8 >> 4, col8 = idx8 & 15;
      split8_store(HkHi + row * LDSS + col8 * 8, HkLo + row * LDSS + col8 * 8, v1);
    }
#pragma unroll
    for (int i = 0; i < 8; ++i){ hs[i] += v0[i]; hs[8 + i] += v1[i]; }
    __syncthreads();

    f32x4 hu[2][2];
#pragma unroll
    for (int ct = 0; ct < 2; ++ct)
#pragma unroll
      for (int rt = 0; rt < 2; ++rt) hu[ct][rt] = zero;

#pragma unroll
    for (int kc = 0; kc < 4; ++kc){
      bf16x8 ah[2], al[2];
#pragma unroll
      for (int rt = 0; rt < 2; ++rt){
        int off = (rt * 16 + m) * LDSS + kc * 32 + q * 8;
        ah[rt] = *(const bf16x8*)(HkHi + off);
        al[rt] = *(const bf16x8*)(HkLo + off);
      }
#pragma unroll
      for (int ct = 0; ct < 2; ++ct){
        int nc = nc0 + ct;
        bf16x8 bh = *(const bf16x8*)(ws + UF_HI + ((kc * 8 + nc) * 64 + lane) * 8);
        bf16x8 bl = *(const bf16x8*)(ws + UF_LO + ((kc * 8 + nc) * 64 + lane) * 8);
#pragma unroll
        for (int rt = 0; rt < 2; ++rt){
          hu[ct][rt] = __builtin_amdgcn_mfma_f32_16x16x32_bf16(ah[rt], bh, hu[ct][rt], 0, 0, 0);
          hu[ct][rt] = __builtin_amdgcn_mfma_f32_16x16x32_bf16(al[rt], bh, hu[ct][rt], 0, 0, 0);
          hu[ct][rt] = __builtin_amdgcn_mfma_f32_16x16x32_bf16(ah[rt], bl, hu[ct][rt], 0, 0, 0);
        }
      }
    }
    // fused forget gate: fc += sigmoid(xWf + h_k U_f + b_f) * c_child_k
#pragma unroll
    for (int ct = 0; ct < 2; ++ct){
      int f = w * 32 + ct * 16 + m;
#pragma unroll
      for (int rt = 0; rt < 2; ++rt){
#pragma unroll
        for (int r = 0; r < 4; ++r){
          int node = node0 + rt * 16 + q * 4 + r;
          float pre = acc[6 + ct][rt][r] + hu[ct][rt][r] + bfv[ct];
          float fg = sigm(pre);
          float cc = ccg[((size_t)node * 4 + k) * 128 + f];
          fc[ct][rt][r] += fg * cc;
        }
      }
    }
  }

  // ---- GEMM3: h_sum @ U_iou, accumulate into iou accumulators ----
  __syncthreads();
  {
    int row = t >> 4, col8 = t & 15;
    split8_store(HkHi + row * LDSS + col8 * 8, HkLo + row * LDSS + col8 * 8, &hs[0]);
  }
  {
    int idx8 = t + 256; int row = idx8 >> 4, col8 = idx8 & 15;
    split8_store(HkHi + row * LDSS + col8 * 8, HkLo + row * LDSS + col8 * 8, &hs[8]);
  }
  __syncthreads();

#pragma unroll
  for (int kc = 0; kc < 4; ++kc){
    bf16x8 ah[2], al[2];
#pragma unroll
    for (int rt = 0; rt < 2; ++rt){
      int off = (rt * 16 + m) * LDSS + kc * 32 + q * 8;
      ah[rt] = *(const bf16x8*)(HkHi + off);
      al[rt] = *(const bf16x8*)(HkLo + off);
    }
#pragma unroll
    for (int c = 0; c < 6; ++c){
      int nc = (c >> 1) * 8 + nc0 + (c & 1);
      bf16x8 bh = *(const bf16x8*)(ws + BH_HI + ((kc * 24 + nc) * 64 + lane) * 8);
      bf16x8 bl = *(const bf16x8*)(ws + BH_LO + ((kc * 24 + nc) * 64 + lane) * 8);
#pragma unroll
      for (int rt = 0; rt < 2; ++rt){
        acc[c][rt] = __builtin_amdgcn_mfma_f32_16x16x32_bf16(ah[rt], bh, acc[c][rt], 0, 0, 0);
        acc[c][rt] = __builtin_amdgcn_mfma_f32_16x16x32_bf16(al[rt], bh, acc[c][rt], 0, 0, 0);
        acc[c][rt] = __builtin_amdgcn_mfma_f32_16x16x32_bf16(ah[rt], bl, acc[c][rt], 0, 0, 0);
      }
    }
  }

  // ---- final epilogue: gates + store h, c ----
  float biv[2], bov[2], buv[2];
#pragma unroll
  for (int ct = 0; ct < 2; ++ct){
    int f = w * 32 + ct * 16 + m;
    biv[ct] = b_iou[f];
    bov[ct] = b_iou[128 + f];
    buv[ct] = b_iou[256 + f];
  }
#pragma unroll
  for (int ct = 0; ct < 2; ++ct){
    int f = w * 32 + ct * 16 + m;
#pragma unroll
    for (int rt = 0; rt < 2; ++rt){
#pragma unroll
      for (int r = 0; r < 4; ++r){
        int node = node0 + rt * 16 + q * 4 + r;
        float iv = sigm(acc[ct][rt][r] + biv[ct]);
        float ov = sigm(acc[2 + ct][rt][r] + bov[ct]);
        float uv = tanh_f(acc[4 + ct][rt][r] + buv[ct]);
        float cv = iv * uv + fc[ct][rt][r];
        float hv = ov * tanh_f(cv);
        out[(size_t)node * 128 + f] = hv;
        out[(size_t)NN * 128 + (size_t)node * 128 + f] = cv;
      }
    }
  }
}

extern "C" void kernel_launch(void* const* d_in, const int* in_sizes, int n_in,
                              void* d_out, int out_size, void* d_ws, size_t ws_size,
                              hipStream_t stream){
  const float* x       = (const float*)d_in[0];
  const float* h_child = (const float*)d_in[1];
  const float* c_child = (const float*)d_in[2];
  const float* W_iou   = (const float*)d_in[3];
  const float* U_iou   = (const float*)d_in[4];
  const float* b_iou   = (const float*)d_in[5];
  const float* W_f     = (const float*)d_in[6];
  const float* U_f     = (const float*)d_in[7];
  const float* b_f     = (const float*)d_in[8];
  unsigned short* ws   = (unsigned short*)d_ws;
  float* out           = (float*)d_out;

  prep_weights<<<512, 256, 0, stream>>>(W_iou, U_iou, W_f, U_f, ws);
  tree_lstm_fused<<<NN / 32, 256, 0, stream>>>(x, h_child, c_child, b_iou, b_f, ws, out);
}